// Round 1
// baseline (119.881 us; speedup 1.0000x reference)
//
#include <hip/hip_runtime.h>

typedef unsigned short ushort_t;
typedef __attribute__((ext_vector_type(8))) short short8;
typedef __attribute__((ext_vector_type(4))) float float4v;
typedef __attribute__((ext_vector_type(2))) unsigned int uint2v;

#define Bn 32
#define Nn 2048
#define Cn 8
#define Fn 128
#define On 128
#define Kn 384   // 3*F
#define MT 16    // rows per workgroup
#define LDSK 392 // Kn + 8 pad (shorts); row stride 784 B

// float -> bf16 bits, round-to-nearest-even (host-side prep kernel only)
__device__ __forceinline__ ushort_t f2bf(float x) {
  unsigned u = __float_as_uint(x);
  u += 0x7fffu + ((u >> 16) & 1u);
  return (ushort_t)(u >> 16);
}

// HW packed f32->bf16 (RNE), 2 elements / instr. T12 recipe: low16 = bf16(lo).
__device__ __forceinline__ unsigned cvt_pk_bf16(float lo, float hi) {
  unsigned r;
  asm("v_cvt_pk_bf16_f32 %0, %1, %2" : "=v"(r) : "v"(lo), "v"(hi));
  return r;
}

__device__ __forceinline__ uint2v pack4(float4v v) {
  uint2v r;
  r.x = cvt_pk_bf16(v.x, v.y);
  r.y = cvt_pk_bf16(v.z, v.w);
  return r;
}

// Pack concat(w_t, w_r, w_l) directly in MFMA B-fragment order (unchanged).
__global__ void prep_w_kernel(const float* __restrict__ w_t,
                              const float* __restrict__ w_l,
                              const float* __restrict__ w_r,
                              ushort_t* __restrict__ wsw) {
  int t = blockIdx.x * blockDim.x + threadIdx.x; // one short8 per thread
  if (t >= 6144) return;                         // 6144*8 = 49152 elements
  int lane = t & 63;
  int r = t >> 6;        // 0..95
  int ks = r % 12;
  int q = r / 12;        // 0..7
  int col = q * 16 + (lane & 15);
  int kbase = ((lane >> 4) * 8) + ks * 32;
  ushort_t* dst = wsw + (size_t)t * 8;
#pragma unroll
  for (int j = 0; j < 8; ++j) {
    int k = kbase + j;
    const float* src = (k < Fn) ? w_t : (k < 2 * Fn) ? w_r : w_l;
    int f = k & (Fn - 1);
    dst[j] = f2bf(src[f * On + col]);
  }
}

// Issue the 9 gather loads (self + 8 children) for one row into register buf.
__device__ __forceinline__ void issue_row(const float* __restrict__ nodes,
                                          int sb, int grp, int ln,
                                          const int4& a, const int4& b,
                                          int it, float4v (&dst)[9]) {
  const int row = it * 4 + grp;
  const int g = sb * MT + row;
  const int base_row = g & ~(Nn - 1);  // b * Nn
  const float4v* np = (const float4v*)nodes;
  dst[0] = np[(size_t)g * (Fn / 4) + ln];  // self (coalesced)
  const int id[Cn] = {a.x, a.y, a.z, a.w, b.x, b.y, b.z, b.w};
#pragma unroll
  for (int c = 0; c < Cn; ++c) {
    // fault-proofing: clamp so a replay with non-pristine `children`
    // cannot fault (no effect on in-range pristine inputs).
    const int ix = id[c] & (Nn - 1);
    dst[1 + c] = np[(size_t)(base_row + ix) * (Fn / 4) + ln];
  }
}

// Consume one row's buffered vectors: coefficients, rr / msum, ll = msum - rr,
// pack to bf16 and write the LDS agg tile.
__device__ __forceinline__ void compute_row(ushort_t* __restrict__ agg,
                                            int grp, int ln,
                                            const int4& a, const int4& b,
                                            int it, const float4v (&v)[9]) {
  const int row = it * 4 + grp;
  const int id[Cn] = {a.x, a.y, a.z, a.w, b.x, b.y, b.z, b.w};
  int ns = 0;
#pragma unroll
  for (int c = 0; c < Cn; ++c) ns += (id[c] != 0) ? 1 : 0;
  const bool single = (ns == 1);
  // one reciprocal per row instead of 8 divides
  const float rden = (ns > 1) ? (1.0f / (float)(ns - 1)) : 0.0f;

  float4v rr = {0.f, 0.f, 0.f, 0.f};
  float4v ms = {0.f, 0.f, 0.f, 0.f};
#pragma unroll
  for (int c = 0; c < Cn; ++c) {
    const float m = (id[c] != 0) ? 1.0f : 0.0f;
    float cr = single ? ((c == 0) ? 0.5f : 0.0f) : ((float)c * rden);
    cr *= m;
    const float4v vc = v[1 + c];
    rr += cr * vc;
    ms += m * vc;   // masked plain sum
  }
  // c_l = (1 - c_r) * mask  =>  agg_l = msum - agg_r
  const float4v ll = ms - rr;

  ushort_t* arow = agg + row * LDSK + ln * 4;
  *(uint2v*)(arow)           = pack4(v[0]);
  *(uint2v*)(arow + Fn)      = pack4(rr);
  *(uint2v*)(arow + 2 * Fn)  = pack4(ll);
}

__device__ __forceinline__ void store_ct(float* __restrict__ out,
                                         const float* __restrict__ bias,
                                         int sb, int l15, int quad, int q,
                                         const float4v& acc) {
  const int col = q * 16 + l15;
  const float bb = bias[col];
  const int grow0 = sb * MT + quad * 4;
#pragma unroll
  for (int r2 = 0; r2 < 4; ++r2) {
    out[(size_t)(grow0 + r2) * On + col] = fmaxf(acc[r2] + bb, 0.f);
  }
}

__global__ __launch_bounds__(128, 3)
void tree_conv_kernel(const float* __restrict__ nodes,
                      const int* __restrict__ children,
                      const ushort_t* __restrict__ wsw,
                      const float* __restrict__ bias,
                      float* __restrict__ out) {
  __shared__ __align__(16) ushort_t agg[MT * LDSK];

  const int tid = threadIdx.x;

  // XCD-locality swizzle: XCD k owns batches 4k..4k+3 (4 MB -> fits 4 MiB L2).
  const int sb = ((blockIdx.x & 7) << 9) | (blockIdx.x >> 3);

  // ---------------- Phase A: 2-deep register-pipelined gather ---------------
  {
    const int grp = tid >> 5;  // 0..3, group g owns rows {it*4+g}
    const int ln = tid & 31;   // lane owns floats [ln*4, ln*4+4)

    int4 ca[4], cb[4];
#pragma unroll
    for (int it = 0; it < 4; ++it) {
      const int g = sb * MT + it * 4 + grp;
      const int4* chv = (const int4*)(children + (size_t)g * Cn);
      ca[it] = chv[0];
      cb[it] = chv[1];
    }

    // Two statically-indexed row buffers (rule #20): row it+1's loads are in
    // flight while row it is consumed -> 9-18 outstanding loads per wave.
    float4v v0[9], v1[9];
    issue_row(nodes, sb, grp, ln, ca[0], cb[0], 0, v0);
    issue_row(nodes, sb, grp, ln, ca[1], cb[1], 1, v1);
    compute_row(agg, grp, ln, ca[0], cb[0], 0, v0);
    issue_row(nodes, sb, grp, ln, ca[2], cb[2], 2, v0);
    compute_row(agg, grp, ln, ca[1], cb[1], 1, v1);
    issue_row(nodes, sb, grp, ln, ca[3], cb[3], 3, v1);
    compute_row(agg, grp, ln, ca[2], cb[2], 2, v0);
    compute_row(agg, grp, ln, ca[3], cb[3], 3, v1);
  }

  // ---------------- Phase B: MFMA --------------------------------------
  const int lane = tid & 63;
  const int wave = tid >> 6;  // 0..1, owns col-tiles q = wave*4 .. wave*4+3
  const int l15 = lane & 15;
  const int quad = lane >> 4;

  // Prefetch B fragments for the first two col-tiles BEFORE the barrier so
  // they are in flight during the barrier wait (counted-vmcnt pattern: the
  // barrier below waits lgkmcnt only, not vmcnt).
  short8 bf0[12], bf1[12];
  const short8* bbase = (const short8*)wsw + lane;
#pragma unroll
  for (int ks = 0; ks < 12; ++ks) bf0[ks] = bbase[((wave * 4 + 0) * 12 + ks) * 64];
#pragma unroll
  for (int ks = 0; ks < 12; ++ks) bf1[ks] = bbase[((wave * 4 + 1) * 12 + ks) * 64];

  // LDS writes visible to all waves; do NOT drain vmcnt (keep bf loads flying).
  asm volatile("s_waitcnt lgkmcnt(0)" ::: "memory");
  __builtin_amdgcn_s_barrier();
  asm volatile("" ::: "memory");

  // A-fragments are col-tile-invariant: read once (12 ds_read_b128, not 48).
  const ushort_t* ar = agg + l15 * LDSK + quad * 8;
  short8 af[12];
#pragma unroll
  for (int ks = 0; ks < 12; ++ks) af[ks] = *(const short8*)(ar + ks * 32);

  float4v acc;

  // ct0
  acc = (float4v){0.f, 0.f, 0.f, 0.f};
#pragma unroll
  for (int ks = 0; ks < 12; ++ks)
    acc = __builtin_amdgcn_mfma_f32_16x16x32_bf16(af[ks], bf0[ks], acc, 0, 0, 0);
  // refill bf0 with q = wave*4+2 while ct1's MFMAs run
#pragma unroll
  for (int ks = 0; ks < 12; ++ks) bf0[ks] = bbase[((wave * 4 + 2) * 12 + ks) * 64];
  store_ct(out, bias, sb, l15, quad, wave * 4 + 0, acc);

  // ct1
  acc = (float4v){0.f, 0.f, 0.f, 0.f};
#pragma unroll
  for (int ks = 0; ks < 12; ++ks)
    acc = __builtin_amdgcn_mfma_f32_16x16x32_bf16(af[ks], bf1[ks], acc, 0, 0, 0);
  // refill bf1 with q = wave*4+3 while ct2's MFMAs run
#pragma unroll
  for (int ks = 0; ks < 12; ++ks) bf1[ks] = bbase[((wave * 4 + 3) * 12 + ks) * 64];
  store_ct(out, bias, sb, l15, quad, wave * 4 + 1, acc);

  // ct2
  acc = (float4v){0.f, 0.f, 0.f, 0.f};
#pragma unroll
  for (int ks = 0; ks < 12; ++ks)
    acc = __builtin_amdgcn_mfma_f32_16x16x32_bf16(af[ks], bf0[ks], acc, 0, 0, 0);
  store_ct(out, bias, sb, l15, quad, wave * 4 + 2, acc);

  // ct3
  acc = (float4v){0.f, 0.f, 0.f, 0.f};
#pragma unroll
  for (int ks = 0; ks < 12; ++ks)
    acc = __builtin_amdgcn_mfma_f32_16x16x32_bf16(af[ks], bf1[ks], acc, 0, 0, 0);
  store_ct(out, bias, sb, l15, quad, wave * 4 + 3, acc);
}

extern "C" void kernel_launch(void* const* d_in, const int* in_sizes, int n_in,
                              void* d_out, int out_size, void* d_ws, size_t ws_size,
                              hipStream_t stream) {
  const float* nodes = (const float*)d_in[0];
  const int* children = (const int*)d_in[1];
  const float* w_t = (const float*)d_in[2];
  const float* w_l = (const float*)d_in[3];
  const float* w_r = (const float*)d_in[4];
  const float* bias = (const float*)d_in[5];
  float* out = (float*)d_out;
  ushort_t* wsw = (ushort_t*)d_ws;  // 49152 bf16 = 96 KiB, fragment-swizzled

  prep_w_kernel<<<24, 256, 0, stream>>>(w_t, w_l, w_r, wsw);
  tree_conv_kernel<<<(Bn * Nn) / MT, 128, 0, stream>>>(nodes, children, wsw, bias, out);
}

// Round 2
// 111.919 us; speedup vs baseline: 1.0711x; 1.0711x over previous
//
#include <hip/hip_runtime.h>

typedef unsigned short ushort_t;
typedef __attribute__((ext_vector_type(8))) short short8;
typedef __attribute__((ext_vector_type(4))) float float4v;
typedef __attribute__((ext_vector_type(2))) unsigned int uint2v;

#define Bn 32
#define Nn 2048
#define Cn 8
#define Fn 128
#define On 128
#define Kn 384   // 3*F
#define MT 64    // rows per workgroup: amortizes the 96 KiB B-stream 4x vs MT=16
#define LDSK 392 // Kn + 8 pad (shorts); row stride 784 B
#define NBLK ((Bn * Nn) / MT)  // 1024 blocks

// float -> bf16 bits, round-to-nearest-even (prep kernel only)
__device__ __forceinline__ ushort_t f2bf(float x) {
  unsigned u = __float_as_uint(x);
  u += 0x7fffu + ((u >> 16) & 1u);
  return (ushort_t)(u >> 16);
}

// HW packed f32->bf16 (RNE), 2 elements / instr.
__device__ __forceinline__ unsigned cvt_pk_bf16(float lo, float hi) {
  unsigned r;
  asm("v_cvt_pk_bf16_f32 %0, %1, %2" : "=v"(r) : "v"(lo), "v"(hi));
  return r;
}

__device__ __forceinline__ uint2v pack4(float4v v) {
  uint2v r;
  r.x = cvt_pk_bf16(v.x, v.y);
  r.y = cvt_pk_bf16(v.z, v.w);
  return r;
}

// Pack concat(w_t, w_r, w_l) directly in MFMA B-fragment order (unchanged).
__global__ void prep_w_kernel(const float* __restrict__ w_t,
                              const float* __restrict__ w_l,
                              const float* __restrict__ w_r,
                              ushort_t* __restrict__ wsw) {
  int t = blockIdx.x * blockDim.x + threadIdx.x; // one short8 per thread
  if (t >= 6144) return;                         // 6144*8 = 49152 elements
  int lane = t & 63;
  int r = t >> 6;        // 0..95
  int ks = r % 12;
  int q = r / 12;        // 0..7
  int col = q * 16 + (lane & 15);
  int kbase = ((lane >> 4) * 8) + ks * 32;
  ushort_t* dst = wsw + (size_t)t * 8;
#pragma unroll
  for (int j = 0; j < 8; ++j) {
    int k = kbase + j;
    const float* src = (k < Fn) ? w_t : (k < 2 * Fn) ? w_r : w_l;
    int f = k & (Fn - 1);
    dst[j] = f2bf(src[f * On + col]);
  }
}

// Issue the 9 gather loads (self + 8 children) for global row g into reg buf.
__device__ __forceinline__ void issue_row(const float* __restrict__ nodes,
                                          int g, int ln,
                                          const int4& a, const int4& b,
                                          float4v (&dst)[9]) {
  const int base_row = g & ~(Nn - 1);  // b * Nn
  const float4v* np = (const float4v*)nodes;
  dst[0] = np[(size_t)g * (Fn / 4) + ln];  // self (coalesced)
  const int id[Cn] = {a.x, a.y, a.z, a.w, b.x, b.y, b.z, b.w};
#pragma unroll
  for (int c = 0; c < Cn; ++c) {
    // fault-proofing clamp: a replay with poisoned `children` cannot fault.
    const int ix = id[c] & (Nn - 1);
    dst[1 + c] = np[(size_t)(base_row + ix) * (Fn / 4) + ln];
  }
}

// Consume one row's buffered vectors: coefficients, rr, ll = msum - rr,
// pack to bf16 and write the LDS agg tile row.
__device__ __forceinline__ void compute_row(ushort_t* __restrict__ agg,
                                            int row, int ln,
                                            const int4& a, const int4& b,
                                            const float4v (&v)[9]) {
  const int id[Cn] = {a.x, a.y, a.z, a.w, b.x, b.y, b.z, b.w};
  int ns = 0;
#pragma unroll
  for (int c = 0; c < Cn; ++c) ns += (id[c] != 0) ? 1 : 0;
  const bool single = (ns == 1);
  const float rden = (ns > 1) ? (1.0f / (float)(ns - 1)) : 0.0f;

  float4v rr = {0.f, 0.f, 0.f, 0.f};
  float4v ms = {0.f, 0.f, 0.f, 0.f};
#pragma unroll
  for (int c = 0; c < Cn; ++c) {
    const float m = (id[c] != 0) ? 1.0f : 0.0f;
    float cr = single ? ((c == 0) ? 0.5f : 0.0f) : ((float)c * rden);
    cr *= m;
    const float4v vc = v[1 + c];
    rr += cr * vc;
    ms += m * vc;  // masked plain sum
  }
  const float4v ll = ms - rr;  // c_l = (1 - c_r) * mask

  ushort_t* arow = agg + row * LDSK + ln * 4;
  *(uint2v*)(arow)          = pack4(v[0]);
  *(uint2v*)(arow + Fn)     = pack4(rr);
  *(uint2v*)(arow + 2 * Fn) = pack4(ll);
}

__global__ __launch_bounds__(256, 3)
void tree_conv_kernel(const float* __restrict__ nodes,
                      const int* __restrict__ children,
                      const ushort_t* __restrict__ wsw,
                      const float* __restrict__ bias,
                      float* __restrict__ out) {
  __shared__ __align__(16) ushort_t agg[MT * LDSK];  // 64 rows x 784 B = 49 KiB

  const int tid = threadIdx.x;

  // XCD-locality swizzle (grid 1024): XCD k owns sb [128k,128k+127] ->
  // batches 4k..4k+3 (4 MB of nodes -> fits the XCD's 4 MiB L2).
  const int sb = ((blockIdx.x & 7) << 7) | (blockIdx.x >> 3);

  // ---------------- Phase A: 2-deep register-pipelined gather ---------------
  // 8 groups of 32 lanes; group owns rows {it*8+grp}, it = 0..7.
  {
    const int grp = tid >> 5;  // 0..7
    const int ln = tid & 31;   // lane owns floats [ln*4, ln*4+4)
    const int g0 = sb * MT + grp;  // global row for it: g0 + it*8

    int4 ca[8], cb[8];
#define LDCH(i)                                                              \
  {                                                                          \
    const int4* chv = (const int4*)(children + (size_t)(g0 + (i)*8) * Cn);   \
    ca[i] = chv[0];                                                          \
    cb[i] = chv[1];                                                          \
  }
    // children prefetched at distance 2 (<=4 pairs live -> low VGPR cost)
    LDCH(0) LDCH(1) LDCH(2)

    float4v v0[9], v1[9];
    issue_row(nodes, g0 + 0 * 8, ln, ca[0], cb[0], v0);
    LDCH(3)
    issue_row(nodes, g0 + 1 * 8, ln, ca[1], cb[1], v1);
    compute_row(agg, 0 * 8 + grp, ln, ca[0], cb[0], v0);
    LDCH(4)
    issue_row(nodes, g0 + 2 * 8, ln, ca[2], cb[2], v0);
    compute_row(agg, 1 * 8 + grp, ln, ca[1], cb[1], v1);
    LDCH(5)
    issue_row(nodes, g0 + 3 * 8, ln, ca[3], cb[3], v1);
    compute_row(agg, 2 * 8 + grp, ln, ca[2], cb[2], v0);
    LDCH(6)
    issue_row(nodes, g0 + 4 * 8, ln, ca[4], cb[4], v0);
    compute_row(agg, 3 * 8 + grp, ln, ca[3], cb[3], v1);
    LDCH(7)
    issue_row(nodes, g0 + 5 * 8, ln, ca[5], cb[5], v1);
    compute_row(agg, 4 * 8 + grp, ln, ca[4], cb[4], v0);
    issue_row(nodes, g0 + 6 * 8, ln, ca[6], cb[6], v0);
    compute_row(agg, 5 * 8 + grp, ln, ca[5], cb[5], v1);
    issue_row(nodes, g0 + 7 * 8, ln, ca[7], cb[7], v1);
    compute_row(agg, 6 * 8 + grp, ln, ca[6], cb[6], v0);
    compute_row(agg, 7 * 8 + grp, ln, ca[7], cb[7], v1);
#undef LDCH
  }

  // ---------------- Phase B: MFMA; each wave = 2 col-tiles x 4 M-tiles ------
  // B-fragments are loaded ONCE per wave (24 KB) and reused across 64 rows:
  // block-level B traffic = 96 KB per 64 rows (was 96 KB per 16 rows).
  const int lane = tid & 63;
  const int wave = tid >> 6;  // 0..3
  const int l15 = lane & 15;
  const int quad = lane >> 4;
  const int ct0 = wave * 2, ct1 = wave * 2 + 1;

  // ALL B loads issue before the barrier (in flight across it: the barrier
  // below waits lgkmcnt only, never drains vmcnt).
  short8 bf0[12], bf1[12];
  const short8* bbase = (const short8*)wsw + lane;
#pragma unroll
  for (int ks = 0; ks < 12; ++ks) bf0[ks] = bbase[(ct0 * 12 + ks) * 64];
#pragma unroll
  for (int ks = 0; ks < 12; ++ks) bf1[ks] = bbase[(ct1 * 12 + ks) * 64];
  const float bb0 = bias[ct0 * 16 + l15];
  const float bb1 = bias[ct1 * 16 + l15];

  asm volatile("s_waitcnt lgkmcnt(0)" ::: "memory");
  __builtin_amdgcn_s_barrier();
  asm volatile("" ::: "memory");

#pragma unroll
  for (int mt = 0; mt < 4; ++mt) {
    const ushort_t* ar = agg + (mt * 16 + l15) * LDSK + quad * 8;
    short8 af[12];
#pragma unroll
    for (int ks = 0; ks < 12; ++ks) af[ks] = *(const short8*)(ar + ks * 32);

    float4v acc0 = {0.f, 0.f, 0.f, 0.f};
    float4v acc1 = {0.f, 0.f, 0.f, 0.f};
#pragma unroll
    for (int ks = 0; ks < 12; ++ks)
      acc0 = __builtin_amdgcn_mfma_f32_16x16x32_bf16(af[ks], bf0[ks], acc0, 0, 0, 0);
#pragma unroll
    for (int ks = 0; ks < 12; ++ks)
      acc1 = __builtin_amdgcn_mfma_f32_16x16x32_bf16(af[ks], bf1[ks], acc1, 0, 0, 0);

    const int grow0 = sb * MT + mt * 16 + quad * 4;
#pragma unroll
    for (int r2 = 0; r2 < 4; ++r2) {
      const size_t ro = (size_t)(grow0 + r2) * On;
      out[ro + ct0 * 16 + l15] = fmaxf(acc0[r2] + bb0, 0.f);
      out[ro + ct1 * 16 + l15] = fmaxf(acc1[r2] + bb1, 0.f);
    }
  }
}

extern "C" void kernel_launch(void* const* d_in, const int* in_sizes, int n_in,
                              void* d_out, int out_size, void* d_ws, size_t ws_size,
                              hipStream_t stream) {
  const float* nodes = (const float*)d_in[0];
  const int* children = (const int*)d_in[1];
  const float* w_t = (const float*)d_in[2];
  const float* w_l = (const float*)d_in[3];
  const float* w_r = (const float*)d_in[4];
  const float* bias = (const float*)d_in[5];
  float* out = (float*)d_out;
  ushort_t* wsw = (ushort_t*)d_ws;  // 49152 bf16 = 96 KiB, fragment-swizzled

  prep_w_kernel<<<24, 256, 0, stream>>>(w_t, w_l, w_r, wsw);
  tree_conv_kernel<<<NBLK, 256, 0, stream>>>(nodes, children, wsw, bias, out);
}

// Round 3
// 110.837 us; speedup vs baseline: 1.0816x; 1.0098x over previous
//
#include <hip/hip_runtime.h>

typedef unsigned short ushort_t;
typedef __attribute__((ext_vector_type(8))) short short8;
typedef __attribute__((ext_vector_type(4))) float float4v;
typedef __attribute__((ext_vector_type(2))) unsigned int uint2v;

#define Bn 32
#define Nn 2048
#define Cn 8
#define Fn 128
#define On 128
#define Kn 384   // 3*F
#define MT 64    // rows per workgroup (keeps B-stream amortized 4x vs MT=16)
#define LDSK 392 // Kn + 8 pad (shorts); row stride 784 B
#define NBLK ((Bn * Nn) / MT)  // 1024 blocks

// float -> bf16 bits, round-to-nearest-even (prep kernel only)
__device__ __forceinline__ ushort_t f2bf(float x) {
  unsigned u = __float_as_uint(x);
  u += 0x7fffu + ((u >> 16) & 1u);
  return (ushort_t)(u >> 16);
}

// HW packed f32->bf16 (RNE), 2 elements / instr.
__device__ __forceinline__ unsigned cvt_pk_bf16(float lo, float hi) {
  unsigned r;
  asm("v_cvt_pk_bf16_f32 %0, %1, %2" : "=v"(r) : "v"(lo), "v"(hi));
  return r;
}

__device__ __forceinline__ uint2v pack4(float4v v) {
  uint2v r;
  r.x = cvt_pk_bf16(v.x, v.y);
  r.y = cvt_pk_bf16(v.z, v.w);
  return r;
}

// Pack concat(w_t, w_r, w_l) directly in MFMA B-fragment order (unchanged).
__global__ void prep_w_kernel(const float* __restrict__ w_t,
                              const float* __restrict__ w_l,
                              const float* __restrict__ w_r,
                              ushort_t* __restrict__ wsw) {
  int t = blockIdx.x * blockDim.x + threadIdx.x; // one short8 per thread
  if (t >= 6144) return;                         // 6144*8 = 49152 elements
  int lane = t & 63;
  int r = t >> 6;        // 0..95
  int ks = r % 12;
  int q = r / 12;        // 0..7
  int col = q * 16 + (lane & 15);
  int kbase = ((lane >> 4) * 8) + ks * 32;
  ushort_t* dst = wsw + (size_t)t * 8;
#pragma unroll
  for (int j = 0; j < 8; ++j) {
    int k = kbase + j;
    const float* src = (k < Fn) ? w_t : (k < 2 * Fn) ? w_r : w_l;
    int f = k & (Fn - 1);
    dst[j] = f2bf(src[f * On + col]);
  }
}

// Issue the 9 gather loads (self + 8 children) for global row g into reg buf.
__device__ __forceinline__ void issue_row(const float* __restrict__ nodes,
                                          int g, int ln,
                                          const int4& a, const int4& b,
                                          float4v (&dst)[9]) {
  const int base_row = g & ~(Nn - 1);  // b * Nn
  const float4v* np = (const float4v*)nodes;
  dst[0] = np[(size_t)g * (Fn / 4) + ln];  // self (coalesced)
  const int id[Cn] = {a.x, a.y, a.z, a.w, b.x, b.y, b.z, b.w};
#pragma unroll
  for (int c = 0; c < Cn; ++c) {
    // fault-proofing clamp: a replay with poisoned `children` cannot fault.
    const int ix = id[c] & (Nn - 1);
    dst[1 + c] = np[(size_t)(base_row + ix) * (Fn / 4) + ln];
  }
}

// Consume one row's buffered vectors: coefficients, rr, ll = msum - rr,
// pack to bf16 and write the LDS agg tile row.
__device__ __forceinline__ void compute_row(ushort_t* __restrict__ agg,
                                            int row, int ln,
                                            const int4& a, const int4& b,
                                            const float4v (&v)[9]) {
  const int id[Cn] = {a.x, a.y, a.z, a.w, b.x, b.y, b.z, b.w};
  int ns = 0;
#pragma unroll
  for (int c = 0; c < Cn; ++c) ns += (id[c] != 0) ? 1 : 0;
  const bool single = (ns == 1);
  const float rden = (ns > 1) ? (1.0f / (float)(ns - 1)) : 0.0f;

  float4v rr = {0.f, 0.f, 0.f, 0.f};
  float4v ms = {0.f, 0.f, 0.f, 0.f};
#pragma unroll
  for (int c = 0; c < Cn; ++c) {
    const float m = (id[c] != 0) ? 1.0f : 0.0f;
    float cr = single ? ((c == 0) ? 0.5f : 0.0f) : ((float)c * rden);
    cr *= m;
    const float4v vc = v[1 + c];
    rr += cr * vc;
    ms += m * vc;  // masked plain sum
  }
  const float4v ll = ms - rr;  // c_l = (1 - c_r) * mask

  ushort_t* arow = agg + row * LDSK + ln * 4;
  *(uint2v*)(arow)          = pack4(v[0]);
  *(uint2v*)(arow + Fn)     = pack4(rr);
  *(uint2v*)(arow + 2 * Fn) = pack4(ll);
}

// 512 threads, 8 waves/block. launch_bounds(512,4): VGPR cap 128 ->
// 2 blocks/CU (16 waves) vs R2's 12 waves; LDS 2x49 KiB = 98 KiB fits.
__global__ __launch_bounds__(512, 4)
void tree_conv_kernel(const float* __restrict__ nodes,
                      const int* __restrict__ children,
                      const ushort_t* __restrict__ wsw,
                      const float* __restrict__ bias,
                      float* __restrict__ out) {
  __shared__ __align__(16) ushort_t agg[MT * LDSK];  // 64 rows x 784 B = 49 KiB

  const int tid = threadIdx.x;

  // XCD-locality swizzle (grid 1024): XCD k owns batches 4k..4k+3
  // (4 MB of nodes -> fits the XCD's 4 MiB L2).
  const int sb = ((blockIdx.x & 7) << 7) | (blockIdx.x >> 3);

  // ---------------- Phase A: 2-deep register-pipelined gather ---------------
  // 16 groups of 32 lanes; group owns rows {it*16+grp}, it = 0..3.
  {
    const int grp = tid >> 5;  // 0..15
    const int ln = tid & 31;   // lane owns floats [ln*4, ln*4+4)
    const int g0 = sb * MT + grp;  // global row for it: g0 + it*16

    int4 ca[4], cb[4];
#define LDCH(i)                                                              \
  {                                                                          \
    const int4* chv = (const int4*)(children + (size_t)(g0 + (i)*16) * Cn);  \
    ca[i] = chv[0];                                                          \
    cb[i] = chv[1];                                                          \
  }
    LDCH(0) LDCH(1)

    float4v v0[9], v1[9];
    issue_row(nodes, g0 + 0 * 16, ln, ca[0], cb[0], v0);
    LDCH(2)
    issue_row(nodes, g0 + 1 * 16, ln, ca[1], cb[1], v1);
    LDCH(3)
    compute_row(agg, 0 * 16 + grp, ln, ca[0], cb[0], v0);
    issue_row(nodes, g0 + 2 * 16, ln, ca[2], cb[2], v0);
    compute_row(agg, 1 * 16 + grp, ln, ca[1], cb[1], v1);
    issue_row(nodes, g0 + 3 * 16, ln, ca[3], cb[3], v1);
    compute_row(agg, 2 * 16 + grp, ln, ca[2], cb[2], v0);
    compute_row(agg, 3 * 16 + grp, ln, ca[3], cb[3], v1);
#undef LDCH
  }

  // ---------------- Phase B: MFMA; each wave = 1 col-tile x 4 M-tiles -------
  // bf is only 48 VGPR/wave now; B traffic unchanged (96 KB per block).
  const int lane = tid & 63;
  const int ct = tid >> 6;  // wave 0..7 owns col-tile ct
  const int l15 = lane & 15;
  const int quad = lane >> 4;

  // B loads issue before the barrier and stay in flight across it
  // (the barrier waits lgkmcnt only, never drains vmcnt).
  short8 bf[12];
  const short8* bbase = (const short8*)wsw + lane;
#pragma unroll
  for (int ks = 0; ks < 12; ++ks) bf[ks] = bbase[(ct * 12 + ks) * 64];
  const float bb = bias[ct * 16 + l15];

  asm volatile("s_waitcnt lgkmcnt(0)" ::: "memory");
  __builtin_amdgcn_s_barrier();
  asm volatile("" ::: "memory");

#pragma unroll
  for (int mt = 0; mt < 4; ++mt) {
    const ushort_t* ar = agg + (mt * 16 + l15) * LDSK + quad * 8;
    short8 af[12];
#pragma unroll
    for (int ks = 0; ks < 12; ++ks) af[ks] = *(const short8*)(ar + ks * 32);

    float4v acc = {0.f, 0.f, 0.f, 0.f};
#pragma unroll
    for (int ks = 0; ks < 12; ++ks)
      acc = __builtin_amdgcn_mfma_f32_16x16x32_bf16(af[ks], bf[ks], acc, 0, 0, 0);

    const int grow0 = sb * MT + mt * 16 + quad * 4;
#pragma unroll
    for (int r2 = 0; r2 < 4; ++r2) {
      out[(size_t)(grow0 + r2) * On + ct * 16 + l15] = fmaxf(acc[r2] + bb, 0.f);
    }
  }
}

extern "C" void kernel_launch(void* const* d_in, const int* in_sizes, int n_in,
                              void* d_out, int out_size, void* d_ws, size_t ws_size,
                              hipStream_t stream) {
  const float* nodes = (const float*)d_in[0];
  const int* children = (const int*)d_in[1];
  const float* w_t = (const float*)d_in[2];
  const float* w_l = (const float*)d_in[3];
  const float* w_r = (const float*)d_in[4];
  const float* bias = (const float*)d_in[5];
  float* out = (float*)d_out;
  ushort_t* wsw = (ushort_t*)d_ws;  // 49152 bf16 = 96 KiB, fragment-swizzled

  prep_w_kernel<<<24, 256, 0, stream>>>(w_t, w_l, w_r, wsw);
  tree_conv_kernel<<<NBLK, 512, 0, stream>>>(nodes, children, wsw, bias, out);
}